// Round 1
// baseline (333.514 us; speedup 1.0000x reference)
//
#include <hip/hip_runtime.h>
#include <hip/hip_bf16.h>

// Chamfer loss: B=32, N=M=2048, D=3.
// loss[b] = 0.5 * ( sum_n ma[n]*min_m d2(a_n,b_m) + sum_m mb[m]*min_n d2(b_m,a_n) )
// with masked pairs forced to BIG^2 = 1e16.
#define B_ 32
#define N_ 2048
#define M_ 2048
#define BIG2 1.0e16f

// Prep: for each direction, each point of the "inner loop" side gets
// float4 {x, y, z, w} where w = mask ? ||p||^2 : 1e16.
// Also zeroes the 32-float output.
__global__ __launch_bounds__(256) void chamfer_prep(
    const int* __restrict__ o_w, const float* __restrict__ o_pts,
    const int* __restrict__ t_w, const float* __restrict__ t_pts,
    float4* __restrict__ prep, float* __restrict__ loss)
{
    int idx = blockIdx.x * 256 + threadIdx.x;     // 0 .. 2*B*M-1
    int dir = idx / (B_ * M_);                    // 0: targets side, 1: outputs side
    int r   = idx - dir * (B_ * M_);              // b*M + m
    const int*   w = (dir == 0) ? t_w   : o_w;
    const float* p = (dir == 0) ? t_pts : o_pts;
    float x = p[r * 3 + 0];
    float y = p[r * 3 + 1];
    float z = p[r * 3 + 2];
    float n2 = fmaf(x, x, fmaf(y, y, z * z));
    float ww = (w[r] != 0) ? n2 : BIG2;
    prep[idx] = make_float4(x, y, z, ww);
    if (idx < B_) loss[idx] = 0.0f;
}

__device__ __forceinline__ void block_reduce_add(float val, float* loss, int b)
{
    // wave reduce (64 lanes)
    #pragma unroll
    for (int off = 32; off > 0; off >>= 1)
        val += __shfl_down(val, off, 64);
    __shared__ float ws4[4];
    int wave = threadIdx.x >> 6;
    int lane = threadIdx.x & 63;
    if (lane == 0) ws4[wave] = val;
    __syncthreads();
    if (threadIdx.x == 0) {
        float s = ws4[0] + ws4[1] + ws4[2] + ws4[3];
        atomicAdd(&loss[b], s);
    }
}

// Main kernel, scalar-load path: the inner-side points come from the prep
// buffer with a wave-uniform address -> compiler should emit s_load (SMEM pipe),
// leaving the VALU with 3 fma + 1 min per pair.
__global__ __launch_bounds__(256) void chamfer_main(
    const int* __restrict__ o_w, const float* __restrict__ o_pts,
    const int* __restrict__ t_w, const float* __restrict__ t_pts,
    const float4* __restrict__ prep, float* __restrict__ loss)
{
    const int dir = blockIdx.z;
    const int b   = blockIdx.y;
    const int n   = blockIdx.x * 256 + threadIdx.x;

    const int*   __restrict__ wa = (dir == 0) ? o_w   : t_w;
    const float* __restrict__ pa = (dir == 0) ? o_pts : t_pts;
    const float4* __restrict__ pb = prep + (size_t)dir * (B_ * M_) + (size_t)b * M_;

    const int ia = b * N_ + n;
    float ax = pa[ia * 3 + 0];
    float ay = pa[ia * 3 + 1];
    float az = pa[ia * 3 + 2];
    float a2  = fmaf(ax, ax, fmaf(ay, ay, az * az));
    float axm = -2.0f * ax, aym = -2.0f * ay, azm = -2.0f * az;

    float mn = INFINITY;
    #pragma unroll 8
    for (int m = 0; m < M_; ++m) {
        float4 t = pb[m];
        float q = fmaf(axm, t.x, fmaf(aym, t.y, fmaf(azm, t.z, t.w)));
        mn = fminf(mn, q);
    }
    float d2  = fmaxf(a2 + mn, 0.0f);      // clamp commutes with min
    float val = (wa[ia] != 0) ? d2 : 0.0f; // row mask
    val *= 0.5f;

    block_reduce_add(val, loss, b);
}

// ---------- Fallback path (if ws too small): LDS staging ----------
__global__ void chamfer_zero(float* __restrict__ loss)
{
    if (threadIdx.x < B_) loss[threadIdx.x] = 0.0f;
}

__global__ __launch_bounds__(256) void chamfer_lds(
    const int* __restrict__ o_w, const float* __restrict__ o_pts,
    const int* __restrict__ t_w, const float* __restrict__ t_pts,
    float* __restrict__ loss)
{
    const int dir = blockIdx.z;
    const int b   = blockIdx.y;
    const int n   = blockIdx.x * 256 + threadIdx.x;

    const int*   __restrict__ wa = (dir == 0) ? o_w   : t_w;
    const float* __restrict__ pa = (dir == 0) ? o_pts : t_pts;
    const int*   __restrict__ wb = (dir == 0) ? t_w   : o_w;
    const float* __restrict__ pb = (dir == 0) ? t_pts : o_pts;

    __shared__ float4 sb[M_];   // 32 KB
    for (int m = threadIdx.x; m < M_; m += 256) {
        int ib = b * M_ + m;
        float x = pb[ib * 3 + 0];
        float y = pb[ib * 3 + 1];
        float z = pb[ib * 3 + 2];
        float n2 = fmaf(x, x, fmaf(y, y, z * z));
        sb[m] = make_float4(x, y, z, (wb[ib] != 0) ? n2 : BIG2);
    }
    __syncthreads();

    const int ia = b * N_ + n;
    float ax = pa[ia * 3 + 0];
    float ay = pa[ia * 3 + 1];
    float az = pa[ia * 3 + 2];
    float a2  = fmaf(ax, ax, fmaf(ay, ay, az * az));
    float axm = -2.0f * ax, aym = -2.0f * ay, azm = -2.0f * az;

    float mn = INFINITY;
    #pragma unroll 8
    for (int m = 0; m < M_; ++m) {
        float4 t = sb[m];
        float q = fmaf(axm, t.x, fmaf(aym, t.y, fmaf(azm, t.z, t.w)));
        mn = fminf(mn, q);
    }
    float d2  = fmaxf(a2 + mn, 0.0f);
    float val = (wa[ia] != 0) ? d2 : 0.0f;
    val *= 0.5f;

    block_reduce_add(val, loss, b);
}

extern "C" void kernel_launch(void* const* d_in, const int* in_sizes, int n_in,
                              void* d_out, int out_size, void* d_ws, size_t ws_size,
                              hipStream_t stream) {
    const int*   o_w   = (const int*)  d_in[0];
    const float* o_pts = (const float*)d_in[1];
    const int*   t_w   = (const int*)  d_in[2];
    const float* t_pts = (const float*)d_in[3];
    float* loss = (float*)d_out;

    const size_t needed = (size_t)2 * B_ * M_ * sizeof(float4);   // 2 MB
    dim3 grid(N_ / 256, B_, 2);

    if (ws_size >= needed) {
        float4* prep = (float4*)d_ws;
        chamfer_prep<<<(2 * B_ * M_) / 256, 256, 0, stream>>>(
            o_w, o_pts, t_w, t_pts, prep, loss);
        chamfer_main<<<grid, 256, 0, stream>>>(
            o_w, o_pts, t_w, t_pts, prep, loss);
    } else {
        chamfer_zero<<<1, 64, 0, stream>>>(loss);
        chamfer_lds<<<grid, 256, 0, stream>>>(
            o_w, o_pts, t_w, t_pts, loss);
    }
}

// Round 2
// 142.270 us; speedup vs baseline: 2.3442x; 2.3442x over previous
//
#include <hip/hip_runtime.h>
#include <hip/hip_bf16.h>

// Chamfer loss: B=32, N=M=2048, D=3.
// loss[b] = 0.5 * ( sum_n ma[n]*min_m d2(a_n,b_m) + sum_m mb[m]*min_n d2(b_m,a_n) )
// masked pairs -> BIG^2 = 1e16 (exact in fp32: ulp(1e16)~1e9 >> |2ab|+a2).
//
// Strategy: per-wave row ownership. Rows (16/wave) live in SGPRs (wave-uniform
// s_loads), the m-side streams coalesced float4 {-2x,-2y,-2z,b2'} per lane.
// Inner loop = 3 v_fma + 1 v_min per (row,pair) — pure VALU, no LDS.
#define B_   32
#define N_   2048
#define M_   2048
#define R_   16          // rows per wave
#define BIG2 1.0e16f

// Prep: per direction, inner-loop-side point m gets {-2x,-2y,-2z, w}
// with w = mask ? ||p||^2 : 1e16. Also zeroes the 32-float output.
__global__ __launch_bounds__(256) void chamfer_prep(
    const int* __restrict__ o_w, const float* __restrict__ o_pts,
    const int* __restrict__ t_w, const float* __restrict__ t_pts,
    float4* __restrict__ prep, float* __restrict__ loss)
{
    int idx = blockIdx.x * 256 + threadIdx.x;     // 0 .. 2*B*M-1
    int dir = idx / (B_ * M_);                    // 0: inner=targets, 1: inner=outputs
    int r   = idx - dir * (B_ * M_);
    const int*   w = (dir == 0) ? t_w   : o_w;
    const float* p = (dir == 0) ? t_pts : o_pts;
    float x = p[r * 3 + 0];
    float y = p[r * 3 + 1];
    float z = p[r * 3 + 2];
    float n2 = fmaf(x, x, fmaf(y, y, z * z));
    float ww = (w[r] != 0) ? n2 : BIG2;
    prep[idx] = make_float4(-2.0f * x, -2.0f * y, -2.0f * z, ww);
    if (idx < B_) loss[idx] = 0.0f;
}

// Main: grid (N_/(4*R_), B_, 2), 256 threads (4 waves), wave w owns rows
// [ (bx*4+w)*R_ , +R_ ).  Lanes stream m in tiles of 64.
__global__ __launch_bounds__(256) void chamfer_main(
    const int* __restrict__ o_w, const float* __restrict__ o_pts,
    const int* __restrict__ t_w, const float* __restrict__ t_pts,
    const float4* __restrict__ prep, float* __restrict__ loss)
{
    const int dir  = blockIdx.z;
    const int b    = blockIdx.y;
    const int lane = threadIdx.x & 63;
    const int wv   = threadIdx.x >> 6;
    const int row0 = (blockIdx.x * 4 + wv) * R_;

    const int*   __restrict__ wa = (dir == 0) ? o_w   : t_w;
    const float* __restrict__ pa = (dir == 0) ? o_pts : t_pts;
    const float4* __restrict__ pb = prep + (size_t)dir * (B_ * M_) + (size_t)b * M_;

    // Wave-uniform row base -> force scalar loads into SGPRs.
    int base = __builtin_amdgcn_readfirstlane((b * N_ + row0) * 3);
    const float* rp = pa + base;
    float rx[R_], ry[R_], rz[R_];
    #pragma unroll
    for (int r = 0; r < R_; ++r) {
        rx[r] = rp[3 * r + 0];
        ry[r] = rp[3 * r + 1];
        rz[r] = rp[3 * r + 2];
    }

    float acc[R_];
    #pragma unroll
    for (int r = 0; r < R_; ++r) acc[r] = 3.4e38f;

    #pragma unroll 4
    for (int t = 0; t < M_ / 64; ++t) {
        float4 q = pb[t * 64 + lane];
        #pragma unroll
        for (int r = 0; r < R_; ++r) {
            // q.x = -2bx etc, q.w = b2'  ->  d = b2' - 2 a.b   (a2 added later)
            float d = fmaf(rx[r], q.x, fmaf(ry[r], q.y, fmaf(rz[r], q.z, q.w)));
            acc[r] = fminf(acc[r], d);
        }
    }

    // Cross-lane min per row (all lanes end with the full min).
    #pragma unroll
    for (int r = 0; r < R_; ++r) {
        float v = acc[r];
        #pragma unroll
        for (int off = 32; off; off >>= 1) v = fminf(v, __shfl_xor(v, off, 64));
        acc[r] = v;
    }

    // Epilogue: add a2, clamp, row mask, sum rows, one atomic per wave.
    int mbase = __builtin_amdgcn_readfirstlane(b * N_ + row0);
    const int* wp = wa + mbase;
    float sum = 0.0f;
    #pragma unroll
    for (int r = 0; r < R_; ++r) {
        float a2 = fmaf(rx[r], rx[r], fmaf(ry[r], ry[r], rz[r] * rz[r]));
        float d2 = fmaxf(a2 + acc[r], 0.0f);
        sum += (wp[r] != 0) ? d2 : 0.0f;
    }
    if (lane == 0) atomicAdd(&loss[b], 0.5f * sum);
}

// ---------- Fallback (ws too small): same structure, build q on the fly ----------
__global__ void chamfer_zero(float* __restrict__ loss)
{
    if (threadIdx.x < B_) loss[threadIdx.x] = 0.0f;
}

__global__ __launch_bounds__(256) void chamfer_nolds(
    const int* __restrict__ o_w, const float* __restrict__ o_pts,
    const int* __restrict__ t_w, const float* __restrict__ t_pts,
    float* __restrict__ loss)
{
    const int dir  = blockIdx.z;
    const int b    = blockIdx.y;
    const int lane = threadIdx.x & 63;
    const int wv   = threadIdx.x >> 6;
    const int row0 = (blockIdx.x * 4 + wv) * R_;

    const int*   __restrict__ wa = (dir == 0) ? o_w   : t_w;
    const float* __restrict__ pa = (dir == 0) ? o_pts : t_pts;
    const int*   __restrict__ wb = (dir == 0) ? t_w   : o_w;
    const float* __restrict__ pb = (dir == 0) ? t_pts : o_pts;

    int base = __builtin_amdgcn_readfirstlane((b * N_ + row0) * 3);
    const float* rp = pa + base;
    float rx[R_], ry[R_], rz[R_];
    #pragma unroll
    for (int r = 0; r < R_; ++r) {
        rx[r] = rp[3 * r + 0];
        ry[r] = rp[3 * r + 1];
        rz[r] = rp[3 * r + 2];
    }
    float acc[R_];
    #pragma unroll
    for (int r = 0; r < R_; ++r) acc[r] = 3.4e38f;

    #pragma unroll 2
    for (int t = 0; t < M_ / 64; ++t) {
        int ib = b * M_ + t * 64 + lane;
        float bx = pb[ib * 3 + 0], by = pb[ib * 3 + 1], bz = pb[ib * 3 + 2];
        float n2 = fmaf(bx, bx, fmaf(by, by, bz * bz));
        float qw = (wb[ib] != 0) ? n2 : BIG2;
        float qx = -2.0f * bx, qy = -2.0f * by, qz = -2.0f * bz;
        #pragma unroll
        for (int r = 0; r < R_; ++r) {
            float d = fmaf(rx[r], qx, fmaf(ry[r], qy, fmaf(rz[r], qz, qw)));
            acc[r] = fminf(acc[r], d);
        }
    }
    #pragma unroll
    for (int r = 0; r < R_; ++r) {
        float v = acc[r];
        #pragma unroll
        for (int off = 32; off; off >>= 1) v = fminf(v, __shfl_xor(v, off, 64));
        acc[r] = v;
    }
    int mbase = __builtin_amdgcn_readfirstlane(b * N_ + row0);
    const int* wp = wa + mbase;
    float sum = 0.0f;
    #pragma unroll
    for (int r = 0; r < R_; ++r) {
        float a2 = fmaf(rx[r], rx[r], fmaf(ry[r], ry[r], rz[r] * rz[r]));
        float d2 = fmaxf(a2 + acc[r], 0.0f);
        sum += (wp[r] != 0) ? d2 : 0.0f;
    }
    if (lane == 0) atomicAdd(&loss[b], 0.5f * sum);
}

extern "C" void kernel_launch(void* const* d_in, const int* in_sizes, int n_in,
                              void* d_out, int out_size, void* d_ws, size_t ws_size,
                              hipStream_t stream) {
    const int*   o_w   = (const int*)  d_in[0];
    const float* o_pts = (const float*)d_in[1];
    const int*   t_w   = (const int*)  d_in[2];
    const float* t_pts = (const float*)d_in[3];
    float* loss = (float*)d_out;

    const size_t needed = (size_t)2 * B_ * M_ * sizeof(float4);   // 2 MB
    dim3 grid(N_ / (4 * R_), B_, 2);                              // (32, 32, 2)

    if (ws_size >= needed) {
        float4* prep = (float4*)d_ws;
        chamfer_prep<<<(2 * B_ * M_) / 256, 256, 0, stream>>>(
            o_w, o_pts, t_w, t_pts, prep, loss);
        chamfer_main<<<grid, 256, 0, stream>>>(
            o_w, o_pts, t_w, t_pts, prep, loss);
    } else {
        chamfer_zero<<<1, 64, 0, stream>>>(loss);
        chamfer_nolds<<<grid, 256, 0, stream>>>(
            o_w, o_pts, t_w, t_pts, loss);
    }
}

// Round 3
// 92.009 us; speedup vs baseline: 3.6248x; 1.5463x over previous
//
#include <hip/hip_runtime.h>
#include <hip/hip_bf16.h>

// Chamfer loss: B=32, N=M=2048, D=3.
// loss[b] = 0.5 * ( sum_n ma[n]*min_m d2(a_n,b_m) + sum_m mb[m]*min_n d2(b_m,a_n) )
// masked pairs -> BIG^2 = 1e16 (exact in fp32: ulp(1e16)~1e9 >> |2ab|+a2).
//
// R3: replace 8192 same-cacheline device atomics (R2's 91us main-kernel cost,
// WRITE_SIZE=256KB) with per-block plain stores + a tiny reduce kernel.
#define B_   32
#define N_   2048
#define M_   2048
#define R_   16          // rows per wave
#define GX_  32          // blocks along N per (b,dir)
#define BIG2 1.0e16f

// Prep: per direction, inner-loop-side point m gets {-2x,-2y,-2z, w}
// with w = mask ? ||p||^2 : 1e16.
__global__ __launch_bounds__(256) void chamfer_prep(
    const int* __restrict__ o_w, const float* __restrict__ o_pts,
    const int* __restrict__ t_w, const float* __restrict__ t_pts,
    float4* __restrict__ prep)
{
    int idx = blockIdx.x * 256 + threadIdx.x;     // 0 .. 2*B*M-1
    int dir = idx / (B_ * M_);                    // 0: inner=targets, 1: inner=outputs
    int r   = idx - dir * (B_ * M_);
    const int*   w = (dir == 0) ? t_w   : o_w;
    const float* p = (dir == 0) ? t_pts : o_pts;
    float x = p[r * 3 + 0];
    float y = p[r * 3 + 1];
    float z = p[r * 3 + 2];
    float n2 = fmaf(x, x, fmaf(y, y, z * z));
    float ww = (w[r] != 0) ? n2 : BIG2;
    prep[idx] = make_float4(-2.0f * x, -2.0f * y, -2.0f * z, ww);
}

// Main: grid (GX_, B_, 2), 256 threads (4 waves), wave wv owns rows
// [ (bx*4+wv)*R_ , +R_ ).  Lanes stream m in tiles of 64.
// Output: one plain store per block -> partials[b*64 + dir*32 + bx].
__global__ __launch_bounds__(256) void chamfer_main(
    const int* __restrict__ o_w, const float* __restrict__ o_pts,
    const int* __restrict__ t_w, const float* __restrict__ t_pts,
    const float4* __restrict__ prep, float* __restrict__ partials)
{
    const int dir  = blockIdx.z;
    const int b    = blockIdx.y;
    const int lane = threadIdx.x & 63;
    const int wv   = threadIdx.x >> 6;
    const int row0 = (blockIdx.x * 4 + wv) * R_;

    const int*   __restrict__ wa = (dir == 0) ? o_w   : t_w;
    const float* __restrict__ pa = (dir == 0) ? o_pts : t_pts;
    const float4* __restrict__ pb = prep + (size_t)dir * (B_ * M_) + (size_t)b * M_;

    // Wave-uniform row base -> scalar loads into SGPRs.
    int base = __builtin_amdgcn_readfirstlane((b * N_ + row0) * 3);
    const float* rp = pa + base;
    float rx[R_], ry[R_], rz[R_];
    #pragma unroll
    for (int r = 0; r < R_; ++r) {
        rx[r] = rp[3 * r + 0];
        ry[r] = rp[3 * r + 1];
        rz[r] = rp[3 * r + 2];
    }

    float acc[R_];
    #pragma unroll
    for (int r = 0; r < R_; ++r) acc[r] = 3.4e38f;

    #pragma unroll 4
    for (int t = 0; t < M_ / 64; ++t) {
        float4 q = pb[t * 64 + lane];
        #pragma unroll
        for (int r = 0; r < R_; ++r) {
            // q.x = -2bx etc, q.w = b2'  ->  d = b2' - 2 a.b   (a2 added later)
            float d = fmaf(rx[r], q.x, fmaf(ry[r], q.y, fmaf(rz[r], q.z, q.w)));
            acc[r] = fminf(acc[r], d);
        }
    }

    // Cross-lane min per row (all lanes end with the full min).
    #pragma unroll
    for (int r = 0; r < R_; ++r) {
        float v = acc[r];
        #pragma unroll
        for (int off = 32; off; off >>= 1) v = fminf(v, __shfl_xor(v, off, 64));
        acc[r] = v;
    }

    // Epilogue: add a2, clamp, row mask, sum rows; block-reduce via LDS; store.
    int mbase = __builtin_amdgcn_readfirstlane(b * N_ + row0);
    const int* wp = wa + mbase;
    float sum = 0.0f;
    #pragma unroll
    for (int r = 0; r < R_; ++r) {
        float a2 = fmaf(rx[r], rx[r], fmaf(ry[r], ry[r], rz[r] * rz[r]));
        float d2 = fmaxf(a2 + acc[r], 0.0f);
        sum += (wp[r] != 0) ? d2 : 0.0f;
    }
    __shared__ float ws4[4];
    if (lane == 0) ws4[wv] = sum;
    __syncthreads();
    if (threadIdx.x == 0)
        partials[b * (2 * GX_) + dir * GX_ + blockIdx.x]
            = ws4[0] + ws4[1] + ws4[2] + ws4[3];
}

// Finish: one block, 256 threads. Thread t: b = t>>3, k = t&7 sums 8 of the
// 64 partials for batch b, then 3-step shfl reduce within the 8-lane group.
__global__ __launch_bounds__(256) void chamfer_finish(
    const float* __restrict__ partials, float* __restrict__ loss)
{
    int t = threadIdx.x;
    int b = t >> 3, k = t & 7;
    const float4* p4 = (const float4*)(partials + b * (2 * GX_) + k * 8);
    float4 u = p4[0], v = p4[1];
    float s = ((u.x + u.y) + (u.z + u.w)) + ((v.x + v.y) + (v.z + v.w));
    #pragma unroll
    for (int off = 4; off; off >>= 1) s += __shfl_xor(s, off, 64);
    if (k == 0) loss[b] = 0.5f * s;
}

// ---------- Fallback (ws too small): prep-on-the-fly + atomics ----------
__global__ void chamfer_zero(float* __restrict__ loss)
{
    if (threadIdx.x < B_) loss[threadIdx.x] = 0.0f;
}

__global__ __launch_bounds__(256) void chamfer_nolds(
    const int* __restrict__ o_w, const float* __restrict__ o_pts,
    const int* __restrict__ t_w, const float* __restrict__ t_pts,
    float* __restrict__ loss)
{
    const int dir  = blockIdx.z;
    const int b    = blockIdx.y;
    const int lane = threadIdx.x & 63;
    const int wv   = threadIdx.x >> 6;
    const int row0 = (blockIdx.x * 4 + wv) * R_;

    const int*   __restrict__ wa = (dir == 0) ? o_w   : t_w;
    const float* __restrict__ pa = (dir == 0) ? o_pts : t_pts;
    const int*   __restrict__ wb = (dir == 0) ? t_w   : o_w;
    const float* __restrict__ pb = (dir == 0) ? t_pts : o_pts;

    int base = __builtin_amdgcn_readfirstlane((b * N_ + row0) * 3);
    const float* rp = pa + base;
    float rx[R_], ry[R_], rz[R_];
    #pragma unroll
    for (int r = 0; r < R_; ++r) {
        rx[r] = rp[3 * r + 0];
        ry[r] = rp[3 * r + 1];
        rz[r] = rp[3 * r + 2];
    }
    float acc[R_];
    #pragma unroll
    for (int r = 0; r < R_; ++r) acc[r] = 3.4e38f;

    #pragma unroll 2
    for (int t = 0; t < M_ / 64; ++t) {
        int ib = b * M_ + t * 64 + lane;
        float bx = pb[ib * 3 + 0], by = pb[ib * 3 + 1], bz = pb[ib * 3 + 2];
        float n2 = fmaf(bx, bx, fmaf(by, by, bz * bz));
        float qw = (wb[ib] != 0) ? n2 : BIG2;
        float qx = -2.0f * bx, qy = -2.0f * by, qz = -2.0f * bz;
        #pragma unroll
        for (int r = 0; r < R_; ++r) {
            float d = fmaf(rx[r], qx, fmaf(ry[r], qy, fmaf(rz[r], qz, qw)));
            acc[r] = fminf(acc[r], d);
        }
    }
    #pragma unroll
    for (int r = 0; r < R_; ++r) {
        float v = acc[r];
        #pragma unroll
        for (int off = 32; off; off >>= 1) v = fminf(v, __shfl_xor(v, off, 64));
        acc[r] = v;
    }
    int mbase = __builtin_amdgcn_readfirstlane(b * N_ + row0);
    const int* wp = wa + mbase;
    float sum = 0.0f;
    #pragma unroll
    for (int r = 0; r < R_; ++r) {
        float a2 = fmaf(rx[r], rx[r], fmaf(ry[r], ry[r], rz[r] * rz[r]));
        float d2 = fmaxf(a2 + acc[r], 0.0f);
        sum += (wp[r] != 0) ? d2 : 0.0f;
    }
    if (lane == 0) atomicAdd(&loss[b], 0.5f * sum);
}

extern "C" void kernel_launch(void* const* d_in, const int* in_sizes, int n_in,
                              void* d_out, int out_size, void* d_ws, size_t ws_size,
                              hipStream_t stream) {
    const int*   o_w   = (const int*)  d_in[0];
    const float* o_pts = (const float*)d_in[1];
    const int*   t_w   = (const int*)  d_in[2];
    const float* t_pts = (const float*)d_in[3];
    float* loss = (float*)d_out;

    const size_t prep_bytes = (size_t)2 * B_ * M_ * sizeof(float4);   // 2 MB
    const size_t part_bytes = (size_t)B_ * 2 * GX_ * sizeof(float);   // 8 KB
    dim3 grid(GX_, B_, 2);                                            // (32, 32, 2)

    if (ws_size >= prep_bytes + part_bytes) {
        float4* prep     = (float4*)d_ws;
        float*  partials = (float*)((char*)d_ws + prep_bytes);
        chamfer_prep<<<(2 * B_ * M_) / 256, 256, 0, stream>>>(
            o_w, o_pts, t_w, t_pts, prep);
        chamfer_main<<<grid, 256, 0, stream>>>(
            o_w, o_pts, t_w, t_pts, prep, partials);
        chamfer_finish<<<1, 256, 0, stream>>>(partials, loss);
    } else {
        chamfer_zero<<<1, 64, 0, stream>>>(loss);
        chamfer_nolds<<<grid, 256, 0, stream>>>(
            o_w, o_pts, t_w, t_pts, loss);
    }
}

// Round 4
// 90.810 us; speedup vs baseline: 3.6727x; 1.0132x over previous
//
#include <hip/hip_runtime.h>
#include <hip/hip_bf16.h>

// Chamfer loss: B=32, N=M=2048, D=3.
// loss[b] = 0.5 * ( sum_n ma[n]*min_m d2(a_n,b_m) + sum_m mb[m]*min_n d2(b_m,a_n) )
// masked pairs -> BIG^2 = 1e16 (exact in fp32: a2 < ulp(1e16)).
//
// R4: fuse prep into main (LDS-staged inner slice, ds_read_b128), pack 2 rows
// per v2f for v_pk_fma_f32 (2.5 VALU inst/pair vs 4), 100%-occupancy config:
// 512 thr (8 waves x 8 rows), 32KB LDS, 4 blocks/CU. No atomics (R3 lesson).
#define B_    32
#define N_    2048
#define M_    2048
#define RW_   8        // rows per wave
#define GX_   32       // n-chunks per (b,dir): 2048 / (8 waves * 8 rows)
#define BIG2  1.0e16f

typedef float v2f __attribute__((ext_vector_type(2)));

__device__ __forceinline__ v2f v2_fma(v2f a, v2f b, v2f c) {
#if __has_builtin(__builtin_elementwise_fma)
    return __builtin_elementwise_fma(a, b, c);
#else
    v2f r; r.x = fmaf(a.x, b.x, c.x); r.y = fmaf(a.y, b.y, c.y); return r;
#endif
}
__device__ __forceinline__ v2f v2_min(v2f a, v2f b) {
#if __has_builtin(__builtin_elementwise_min)
    return __builtin_elementwise_min(a, b);
#else
    v2f r; r.x = fminf(a.x, b.x); r.y = fminf(a.y, b.y); return r;
#endif
}

// Main: grid (GX_, B_, 2), 512 threads (8 waves). Wave wv owns rows
// [bx*64 + wv*8, +8). Block stages its (b,dir) inner slice into LDS as
// float4 {-2x,-2y,-2z, mask? |p|^2 : 1e16}, then streams 64 points/tile.
__global__ __launch_bounds__(512, 8) void chamfer_main(
    const int* __restrict__ o_w, const float* __restrict__ o_pts,
    const int* __restrict__ t_w, const float* __restrict__ t_pts,
    float* __restrict__ partials)
{
    const int dir  = blockIdx.z;
    const int b    = blockIdx.y;
    const int tid  = threadIdx.x;
    const int lane = tid & 63;
    const int wv   = tid >> 6;
    const int row0 = blockIdx.x * (8 * RW_) + wv * RW_;

    const int*   wa; const float* pa;   // outer (row) side
    const int*   wb; const float* pb;   // inner (streamed) side
    if (dir == 0) { wa = o_w; pa = o_pts; wb = t_w; pb = t_pts; }
    else          { wa = t_w; pa = t_pts; wb = o_w; pb = o_pts; }

    __shared__ float4 sq[M_];           // 32 KB
    __shared__ float  wsum[8];

    // ---- Stage inner slice: 512 threads x 2 point-pairs, coalesced float2.
    {
        const float2* src2 = (const float2*)(pb + (size_t)b * M_ * 3);
        const int2*   wb2  = (const int2*)(wb + (size_t)b * M_);
        #pragma unroll
        for (int k = 0; k < 2; ++k) {
            int p = tid + k * 512;                     // pair index 0..1023
            float2 u0 = src2[p * 3 + 0];
            float2 u1 = src2[p * 3 + 1];
            float2 u2 = src2[p * 3 + 2];
            int2   mm = wb2[p];
            float x0 = u0.x, y0 = u0.y, z0 = u1.x;
            float x1 = u1.y, y1 = u2.x, z1 = u2.y;
            float n20 = fmaf(x0, x0, fmaf(y0, y0, z0 * z0));
            float n21 = fmaf(x1, x1, fmaf(y1, y1, z1 * z1));
            sq[2 * p]     = make_float4(-2.f * x0, -2.f * y0, -2.f * z0,
                                        mm.x ? n20 : BIG2);
            sq[2 * p + 1] = make_float4(-2.f * x1, -2.f * y1, -2.f * z1,
                                        mm.y ? n21 : BIG2);
        }
    }

    // ---- Row constants: 4 row-pairs packed {row 2j, row 2j+1} per v2f.
    v2f rx2[4], ry2[4], rz2[4];
    {
        const float* rp = pa + (size_t)(b * N_ + row0) * 3;
        #pragma unroll
        for (int j = 0; j < 4; ++j) {
            rx2[j] = (v2f){ rp[(2 * j) * 3 + 0], rp[(2 * j + 1) * 3 + 0] };
            ry2[j] = (v2f){ rp[(2 * j) * 3 + 1], rp[(2 * j + 1) * 3 + 1] };
            rz2[j] = (v2f){ rp[(2 * j) * 3 + 2], rp[(2 * j + 1) * 3 + 2] };
        }
    }
    __syncthreads();

    v2f acc[4];
    #pragma unroll
    for (int j = 0; j < 4; ++j) acc[j] = (v2f){ 3.4e38f, 3.4e38f };

    // ---- Inner loop: 32 tiles of 64 points. Per tile per row-pair:
    // 3 v_pk_fma + 2 v_min (2.5 VALU inst per point-row pair).
    #pragma unroll 2
    for (int t = 0; t < M_ / 64; ++t) {
        float4 q = sq[t * 64 + lane];
        v2f qx = (v2f){ q.x, q.x };
        v2f qy = (v2f){ q.y, q.y };
        v2f qz = (v2f){ q.z, q.z };
        v2f qw = (v2f){ q.w, q.w };
        #pragma unroll
        for (int j = 0; j < 4; ++j) {
            v2f d = v2_fma(rx2[j], qx, v2_fma(ry2[j], qy, v2_fma(rz2[j], qz, qw)));
            acc[j] = v2_min(acc[j], d);
        }
    }

    // ---- Cross-lane min per row, epilogue, block reduce, one store.
    const int* wp = wa + (size_t)b * N_ + row0;
    float sum = 0.0f;
    #pragma unroll
    for (int j = 0; j < 4; ++j) {
        float m0 = acc[j].x, m1 = acc[j].y;
        #pragma unroll
        for (int off = 32; off; off >>= 1) {
            m0 = fminf(m0, __shfl_xor(m0, off, 64));
            m1 = fminf(m1, __shfl_xor(m1, off, 64));
        }
        float a20 = fmaf(rx2[j].x, rx2[j].x,
                    fmaf(ry2[j].x, ry2[j].x, rz2[j].x * rz2[j].x));
        float a21 = fmaf(rx2[j].y, rx2[j].y,
                    fmaf(ry2[j].y, ry2[j].y, rz2[j].y * rz2[j].y));
        float d20 = fmaxf(a20 + m0, 0.0f);
        float d21 = fmaxf(a21 + m1, 0.0f);
        sum += (wp[2 * j]     != 0) ? d20 : 0.0f;
        sum += (wp[2 * j + 1] != 0) ? d21 : 0.0f;
    }
    if (lane == 0) wsum[wv] = sum;
    __syncthreads();
    if (tid == 0) {
        float s = 0.f;
        #pragma unroll
        for (int i = 0; i < 8; ++i) s += wsum[i];
        partials[((size_t)b * 2 + dir) * GX_ + blockIdx.x] = s;
    }
}

// Finish: one block, 256 threads. Thread t: b = t>>3, k = t&7 sums 8 of the
// 64 partials for batch b, then 3-step shfl reduce within the 8-lane group.
__global__ __launch_bounds__(256) void chamfer_finish(
    const float* __restrict__ partials, float* __restrict__ loss)
{
    int t = threadIdx.x;
    int b = t >> 3, k = t & 7;
    const float4* p4 = (const float4*)(partials + b * (2 * GX_) + k * 8);
    float4 u = p4[0], v = p4[1];
    float s = ((u.x + u.y) + (u.z + u.w)) + ((v.x + v.y) + (v.z + v.w));
    #pragma unroll
    for (int off = 4; off; off >>= 1) s += __shfl_xor(s, off, 64);
    if (k == 0) loss[b] = 0.5f * s;
}

// ---------- Fallback (ws too small): prep-on-the-fly + atomics ----------
__global__ void chamfer_zero(float* __restrict__ loss)
{
    if (threadIdx.x < B_) loss[threadIdx.x] = 0.0f;
}

__global__ __launch_bounds__(256) void chamfer_nolds(
    const int* __restrict__ o_w, const float* __restrict__ o_pts,
    const int* __restrict__ t_w, const float* __restrict__ t_pts,
    float* __restrict__ loss)
{
    const int dir  = blockIdx.z;
    const int b    = blockIdx.y;
    const int lane = threadIdx.x & 63;
    const int wv   = threadIdx.x >> 6;
    const int row0 = (blockIdx.x * 4 + wv) * 16;

    const int*   __restrict__ wa = (dir == 0) ? o_w   : t_w;
    const float* __restrict__ pa = (dir == 0) ? o_pts : t_pts;
    const int*   __restrict__ wb = (dir == 0) ? t_w   : o_w;
    const float* __restrict__ pb = (dir == 0) ? t_pts : o_pts;

    int base = __builtin_amdgcn_readfirstlane((b * N_ + row0) * 3);
    const float* rp = pa + base;
    float rx[16], ry[16], rz[16];
    #pragma unroll
    for (int r = 0; r < 16; ++r) {
        rx[r] = rp[3 * r + 0];
        ry[r] = rp[3 * r + 1];
        rz[r] = rp[3 * r + 2];
    }
    float acc[16];
    #pragma unroll
    for (int r = 0; r < 16; ++r) acc[r] = 3.4e38f;

    #pragma unroll 2
    for (int t = 0; t < M_ / 64; ++t) {
        int ib = b * M_ + t * 64 + lane;
        float bx = pb[ib * 3 + 0], by = pb[ib * 3 + 1], bz = pb[ib * 3 + 2];
        float n2 = fmaf(bx, bx, fmaf(by, by, bz * bz));
        float qw = (wb[ib] != 0) ? n2 : BIG2;
        float qx = -2.0f * bx, qy = -2.0f * by, qz = -2.0f * bz;
        #pragma unroll
        for (int r = 0; r < 16; ++r) {
            float d = fmaf(rx[r], qx, fmaf(ry[r], qy, fmaf(rz[r], qz, qw)));
            acc[r] = fminf(acc[r], d);
        }
    }
    #pragma unroll
    for (int r = 0; r < 16; ++r) {
        float v = acc[r];
        #pragma unroll
        for (int off = 32; off; off >>= 1) v = fminf(v, __shfl_xor(v, off, 64));
        acc[r] = v;
    }
    int mbase = __builtin_amdgcn_readfirstlane(b * N_ + row0);
    const int* wp = wa + mbase;
    float sum = 0.0f;
    #pragma unroll
    for (int r = 0; r < 16; ++r) {
        float a2 = fmaf(rx[r], rx[r], fmaf(ry[r], ry[r], rz[r] * rz[r]));
        float d2 = fmaxf(a2 + acc[r], 0.0f);
        sum += (wp[r] != 0) ? d2 : 0.0f;
    }
    if (lane == 0) atomicAdd(&loss[b], 0.5f * sum);
}

extern "C" void kernel_launch(void* const* d_in, const int* in_sizes, int n_in,
                              void* d_out, int out_size, void* d_ws, size_t ws_size,
                              hipStream_t stream) {
    const int*   o_w   = (const int*)  d_in[0];
    const float* o_pts = (const float*)d_in[1];
    const int*   t_w   = (const int*)  d_in[2];
    const float* t_pts = (const float*)d_in[3];
    float* loss = (float*)d_out;

    const size_t part_bytes = (size_t)B_ * 2 * GX_ * sizeof(float);   // 8 KB

    if (ws_size >= part_bytes) {
        float* partials = (float*)d_ws;
        dim3 grid(GX_, B_, 2);                                        // (32, 32, 2)
        chamfer_main<<<grid, 512, 0, stream>>>(
            o_w, o_pts, t_w, t_pts, partials);
        chamfer_finish<<<1, 256, 0, stream>>>(partials, loss);
    } else {
        chamfer_zero<<<1, 64, 0, stream>>>(loss);
        dim3 grid(N_ / 64, B_, 2);
        chamfer_nolds<<<grid, 256, 0, stream>>>(
            o_w, o_pts, t_w, t_pts, loss);
    }
}

// Round 5
// 85.287 us; speedup vs baseline: 3.9105x; 1.0648x over previous
//
#include <hip/hip_runtime.h>
#include <hip/hip_bf16.h>

// Chamfer loss: B=32, N=M=2048, D=3.
// loss[b] = 0.5 * ( sum_n ma[n]*min_m d2(a_n,b_m) + sum_m mb[m]*min_n d2(b_m,a_n) )
// masked pairs -> BIG^2 = 1e16 (exact in fp32: a2 < ulp(1e16)).
//
// R5: point-pair packing for v_pk_fma_f32 with SoA-interleaved LDS (pk operands
// are natural reg pairs from ds_read_b128, zero per-tile splat cost), rows in
// SGPRs (R2-verified readfirstlane trick), __launch_bounds__(512) WITHOUT a
// min-waves cap (R4's (512,8) forced a 64-VGPR budget -> suspected silent
// scratch spill = the unexplained 4x), 1-deep LDS prefetch pipeline.
#define B_    32
#define N_    2048
#define M_    2048
#define RW_   8        // rows per wave
#define GX_   32       // n-chunks per (b,dir): 2048 / (8 waves * 8 rows)
#define BIG2  1.0e16f

typedef float v2f __attribute__((ext_vector_type(2)));

__device__ __forceinline__ v2f v2_fma(v2f a, v2f b, v2f c) {
#if __has_builtin(__builtin_elementwise_fma)
    return __builtin_elementwise_fma(a, b, c);
#else
    v2f r; r.x = fmaf(a.x, b.x, c.x); r.y = fmaf(a.y, b.y, c.y); return r;
#endif
}
__device__ __forceinline__ v2f v2_min(v2f a, v2f b) {
#if __has_builtin(__builtin_elementwise_min)
    return __builtin_elementwise_min(a, b);
#else
    v2f r; r.x = fminf(a.x, b.x); r.y = fminf(a.y, b.y); return r;
#endif
}
__device__ __forceinline__ v2f v2_splat(float s) { return (v2f){ s, s }; }

union F4V2 { float4 f4; struct { v2f lo, hi; } v; };

// Main: grid (GX_, B_, 2), 512 threads (8 waves). Wave wv owns rows
// [bx*64 + wv*8, +8) in SGPRs. Inner side staged in LDS as point-PAIR SoA:
//   sqA[p] = {-2x_{2p}, -2x_{2p+1}, -2y_{2p}, -2y_{2p+1}}
//   sqB[p] = {-2z_{2p}, -2z_{2p+1},  w_{2p},   w_{2p+1}}   (w = mask?|p|^2:1e16)
// Tile = 64 lanes x 2 points = 128 points; per tile: 2 ds_read_b128 +
// (3 pk_fma + 1 pk_min) x 8 rows.
__global__ __launch_bounds__(512) void chamfer_main(
    const int* __restrict__ o_w, const float* __restrict__ o_pts,
    const int* __restrict__ t_w, const float* __restrict__ t_pts,
    float* __restrict__ partials)
{
    const int dir  = blockIdx.z;
    const int b    = blockIdx.y;
    const int tid  = threadIdx.x;
    const int lane = tid & 63;
    const int wv   = tid >> 6;
    const int row0 = blockIdx.x * (8 * RW_) + wv * RW_;

    const int*   wa; const float* pa;   // outer (row) side
    const int*   wb; const float* pb;   // inner (streamed) side
    if (dir == 0) { wa = o_w; pa = o_pts; wb = t_w; pb = t_pts; }
    else          { wa = t_w; pa = t_pts; wb = o_w; pb = o_pts; }

    __shared__ float4 sqA[M_ / 2];      // 16 KB
    __shared__ float4 sqB[M_ / 2];      // 16 KB
    __shared__ float  wsum[8];

    // ---- Stage inner slice: 512 threads x 2 pair-slots, coalesced float2.
    {
        const float2* src2 = (const float2*)(pb + (size_t)b * M_ * 3);
        const int2*   wb2  = (const int2*)(wb + (size_t)b * M_);
        #pragma unroll
        for (int k = 0; k < 2; ++k) {
            int p = tid + k * 512;                     // pair index 0..1023
            float2 u0 = src2[p * 3 + 0];
            float2 u1 = src2[p * 3 + 1];
            float2 u2 = src2[p * 3 + 2];
            int2   mm = wb2[p];
            float x0 = u0.x, y0 = u0.y, z0 = u1.x;
            float x1 = u1.y, y1 = u2.x, z1 = u2.y;
            float n20 = fmaf(x0, x0, fmaf(y0, y0, z0 * z0));
            float n21 = fmaf(x1, x1, fmaf(y1, y1, z1 * z1));
            sqA[p] = make_float4(-2.f * x0, -2.f * x1, -2.f * y0, -2.f * y1);
            sqB[p] = make_float4(-2.f * z0, -2.f * z1,
                                 mm.x ? n20 : BIG2, mm.y ? n21 : BIG2);
        }
    }

    // ---- Row constants into SGPRs (wave-uniform base -> s_loads).
    int base = __builtin_amdgcn_readfirstlane((b * N_ + row0) * 3);
    const float* rp = pa + base;
    float rx[RW_], ry[RW_], rz[RW_];
    #pragma unroll
    for (int r = 0; r < RW_; ++r) {
        rx[r] = rp[3 * r + 0];
        ry[r] = rp[3 * r + 1];
        rz[r] = rp[3 * r + 2];
    }
    __syncthreads();

    v2f acc[RW_];
    #pragma unroll
    for (int r = 0; r < RW_; ++r) acc[r] = v2_splat(3.4e38f);

    // ---- Inner loop: 16 tiles of 128 points, 1-deep LDS prefetch.
    F4V2 qa, qb, na, nb;
    qa.f4 = sqA[lane];
    qb.f4 = sqB[lane];
    #pragma unroll 4
    for (int t = 0; t < M_ / 128; ++t) {
        if (t + 1 < M_ / 128) {
            na.f4 = sqA[(t + 1) * 64 + lane];
            nb.f4 = sqB[(t + 1) * 64 + lane];
        }
        v2f xs = qa.v.lo, ys = qa.v.hi, zs = qb.v.lo, ws = qb.v.hi;
        #pragma unroll
        for (int r = 0; r < RW_; ++r) {
            v2f d = v2_fma(v2_splat(rx[r]), xs,
                    v2_fma(v2_splat(ry[r]), ys,
                    v2_fma(v2_splat(rz[r]), zs, ws)));
            acc[r] = v2_min(acc[r], d);
        }
        qa = na; qb = nb;
    }

    // ---- Cross-lane min per row, epilogue, block reduce, one store.
    int mbase = __builtin_amdgcn_readfirstlane(b * N_ + row0);
    const int* wp = wa + mbase;
    float sum = 0.0f;
    #pragma unroll
    for (int r = 0; r < RW_; ++r) {
        float m = fminf(acc[r].x, acc[r].y);
        #pragma unroll
        for (int off = 32; off; off >>= 1)
            m = fminf(m, __shfl_xor(m, off, 64));
        float a2 = fmaf(rx[r], rx[r], fmaf(ry[r], ry[r], rz[r] * rz[r]));
        float d2 = fmaxf(a2 + m, 0.0f);
        sum += (wp[r] != 0) ? d2 : 0.0f;
    }
    if (lane == 0) wsum[wv] = sum;
    __syncthreads();
    if (tid == 0) {
        float s = 0.f;
        #pragma unroll
        for (int i = 0; i < 8; ++i) s += wsum[i];
        partials[((size_t)b * 2 + dir) * GX_ + blockIdx.x] = s;
    }
}

// Finish: one block, 256 threads. Thread t: b = t>>3, k = t&7 sums 8 of the
// 64 partials for batch b, then 3-step shfl reduce within the 8-lane group.
__global__ __launch_bounds__(256) void chamfer_finish(
    const float* __restrict__ partials, float* __restrict__ loss)
{
    int t = threadIdx.x;
    int b = t >> 3, k = t & 7;
    const float4* p4 = (const float4*)(partials + b * (2 * GX_) + k * 8);
    float4 u = p4[0], v = p4[1];
    float s = ((u.x + u.y) + (u.z + u.w)) + ((v.x + v.y) + (v.z + v.w));
    #pragma unroll
    for (int off = 4; off; off >>= 1) s += __shfl_xor(s, off, 64);
    if (k == 0) loss[b] = 0.5f * s;
}

// ---------- Fallback (ws too small): prep-on-the-fly + atomics ----------
__global__ void chamfer_zero(float* __restrict__ loss)
{
    if (threadIdx.x < B_) loss[threadIdx.x] = 0.0f;
}

__global__ __launch_bounds__(256) void chamfer_nolds(
    const int* __restrict__ o_w, const float* __restrict__ o_pts,
    const int* __restrict__ t_w, const float* __restrict__ t_pts,
    float* __restrict__ loss)
{
    const int dir  = blockIdx.z;
    const int b    = blockIdx.y;
    const int lane = threadIdx.x & 63;
    const int wv   = threadIdx.x >> 6;
    const int row0 = (blockIdx.x * 4 + wv) * 16;

    const int*   __restrict__ wa = (dir == 0) ? o_w   : t_w;
    const float* __restrict__ pa = (dir == 0) ? o_pts : t_pts;
    const int*   __restrict__ wb = (dir == 0) ? t_w   : o_w;
    const float* __restrict__ pb = (dir == 0) ? t_pts : o_pts;

    int base = __builtin_amdgcn_readfirstlane((b * N_ + row0) * 3);
    const float* rp = pa + base;
    float rx[16], ry[16], rz[16];
    #pragma unroll
    for (int r = 0; r < 16; ++r) {
        rx[r] = rp[3 * r + 0];
        ry[r] = rp[3 * r + 1];
        rz[r] = rp[3 * r + 2];
    }
    float acc[16];
    #pragma unroll
    for (int r = 0; r < 16; ++r) acc[r] = 3.4e38f;

    #pragma unroll 2
    for (int t = 0; t < M_ / 64; ++t) {
        int ib = b * M_ + t * 64 + lane;
        float bx = pb[ib * 3 + 0], by = pb[ib * 3 + 1], bz = pb[ib * 3 + 2];
        float n2 = fmaf(bx, bx, fmaf(by, by, bz * bz));
        float qw = (wb[ib] != 0) ? n2 : BIG2;
        float qx = -2.0f * bx, qy = -2.0f * by, qz = -2.0f * bz;
        #pragma unroll
        for (int r = 0; r < 16; ++r) {
            float d = fmaf(rx[r], qx, fmaf(ry[r], qy, fmaf(rz[r], qz, qw)));
            acc[r] = fminf(acc[r], d);
        }
    }
    #pragma unroll
    for (int r = 0; r < 16; ++r) {
        float v = acc[r];
        #pragma unroll
        for (int off = 32; off; off >>= 1) v = fminf(v, __shfl_xor(v, off, 64));
        acc[r] = v;
    }
    int mbase = __builtin_amdgcn_readfirstlane(b * N_ + row0);
    const int* wp = wa + mbase;
    float sum = 0.0f;
    #pragma unroll
    for (int r = 0; r < 16; ++r) {
        float a2 = fmaf(rx[r], rx[r], fmaf(ry[r], ry[r], rz[r] * rz[r]));
        float d2 = fmaxf(a2 + acc[r], 0.0f);
        sum += (wp[r] != 0) ? d2 : 0.0f;
    }
    if (lane == 0) atomicAdd(&loss[b], 0.5f * sum);
}

extern "C" void kernel_launch(void* const* d_in, const int* in_sizes, int n_in,
                              void* d_out, int out_size, void* d_ws, size_t ws_size,
                              hipStream_t stream) {
    const int*   o_w   = (const int*)  d_in[0];
    const float* o_pts = (const float*)d_in[1];
    const int*   t_w   = (const int*)  d_in[2];
    const float* t_pts = (const float*)d_in[3];
    float* loss = (float*)d_out;

    const size_t part_bytes = (size_t)B_ * 2 * GX_ * sizeof(float);   // 8 KB

    if (ws_size >= part_bytes) {
        float* partials = (float*)d_ws;
        dim3 grid(GX_, B_, 2);                                        // (32, 32, 2)
        chamfer_main<<<grid, 512, 0, stream>>>(
            o_w, o_pts, t_w, t_pts, partials);
        chamfer_finish<<<1, 256, 0, stream>>>(partials, loss);
    } else {
        chamfer_zero<<<1, 64, 0, stream>>>(loss);
        dim3 grid(N_ / 64, B_, 2);
        chamfer_nolds<<<grid, 256, 0, stream>>>(
            o_w, o_pts, t_w, t_pts, loss);
    }
}